// Round 8
// baseline (259.083 us; speedup 1.0000x reference)
//
#include <hip/hip_runtime.h>

#define HDIM   64
#define TSTEPS 5
#define WAVES  4
#define BLOCK  (WAVES * 64)
#define GPW    2                    // batch groups (of 16) per wave
#define EPW    (GPW * 16)           // 32 batch per wave
#define EPB    (WAVES * EPW)        // 128 batch per block

typedef _Float16 f16x8 __attribute__((ext_vector_type(8)));
typedef float    f32x4 __attribute__((ext_vector_type(4)));

#define L2E 1.44269504088896340736f   // log2(e)

__device__ __forceinline__ float rcp_(float x) { return __builtin_amdgcn_rcpf(x); }
__device__ __forceinline__ float ex2_(float x) { return __builtin_amdgcn_exp2f(x); }

// Gates as D[m=batch e][n=gate row j'] = A[e][k] * B[k][j'] + C(bias + x*W_ih)
// B = W_hh^T staged once in LDS (pre-scaled by log2e; 2*log2e for g-gate).
// GPW=2 M-groups per wave: every Wf fragment read feeds 2 MFMAs.
//
// REGISTER BUDGET (R5-R7): GPW=2 clean allocation is 128 VGPRs, but capping
// at exactly 128 (launch_bounds .,4 with 512 threads) makes the allocator
// spill 1.3 GB to scratch. Cap must sit ABOVE the live set: (256,3) -> 168.
//
// OCCUPANCY (R7): WAVES=8 -> 66 KB LDS -> 2 blocks/CU -> SIMDs starved
// (VALUBusy 60%). WAVES=4 -> 50 KB -> 3 blocks/CU = 12 waves/CU = 3/SIMD.
//
// 16x16x32 f16 layouts (verified R3-R7, absmax 9.8e-4):
//   A-frag: lane holds A[m=lane&15][k = kh*32 + (lane>>4)*8 + i], i=0..7
//   B-frag: lane holds B[k = kh*32 + (lane>>4)*8 + i][n = ntile*16 + (lane&15)]
//   C/D:    lane holds D[m = (lane>>4)*4 + reg][n = ntile*16 + (lane&15)]
__global__ __launch_bounds__(BLOCK, 3) void lstm_mfma_kernel(
    const float* __restrict__ x,      // [B, T, 1]
    const float* __restrict__ W_ih,   // [256, 1]
    const float* __restrict__ W_hh,   // [256, 64]
    const float* __restrict__ b_ih,   // [256]
    const float* __restrict__ b_hh,   // [256]
    const float* __restrict__ W_fc,   // [1, 64]
    const float* __restrict__ b_fc,   // [1]
    float* __restrict__ out,          // [B, 1]
    int B)
{
    __shared__ _Float16 Wf[2048 * 8];               // 32 KB, B-fragments
    __shared__ _Float16 hbuf[WAVES * GPW * 1024];   // 16 KB, per-wave/group h A-frags
    __shared__ float    wih4[256];                  // [jl*4+G], pre-scaled
    __shared__ float    cb4[256];                   // [jl*4+G], pre-scaled b_ih+b_hh

    const int tid = threadIdx.x;

    // ---- one-time staging ----
    #pragma unroll
    for (int s0 = 0; s0 < 2048; s0 += BLOCK) {
        const int s  = s0 + tid;
        const int ln = s & 63;
        const int kh = (s >> 6) & 1;
        const int n  = s >> 7;                             // N-tile, gate G = n>>2
        const float scl = ((n >> 2) == 2) ? (2.0f * L2E) : L2E;
        const int j  = n * 16 + (ln & 15);
        const int k0 = kh * 32 + ((ln >> 4) & 3) * 8;
        const float* src = W_hh + j * HDIM + k0;
        #pragma unroll
        for (int i = 0; i < 8; i++)
            Wf[s * 8 + i] = (_Float16)(src[i] * scl);
    }
    if (tid < 256) {
        const int jl = tid >> 2, G = tid & 3;
        const float scl = (G == 2) ? (2.0f * L2E) : L2E;
        wih4[tid] = W_ih[G * 64 + jl] * scl;
        cb4[tid]  = (b_ih[G * 64 + jl] + b_hh[G * 64 + jl]) * scl;
    }
    __syncthreads();   // only barrier

    const int lane = tid & 63;
    const int wave = tid >> 6;
    const int m    = lane & 15;
    const int q    = lane >> 4;
    const int eg0  = (blockIdx.x * WAVES + wave) * EPW;

    _Float16* hb = hbuf + wave * (GPW * 1024);

    // x element offsets: e = eg0 + g*16 + q*4 + r  -> offset e*TSTEPS (+ r*TSTEPS + t)
    int xo[GPW];
    #pragma unroll
    for (int g = 0; g < GPW; g++) {
        int e4 = eg0 + g * 16 + q * 4;
        if (e4 > B - 4) e4 = (B >= 4) ? (B - 4) : 0;   // defensive; grid is exact
        xo[g] = e4 * TSTEPS;
    }

    float c[GPW][16];   // cell state, scaled by 2*log2e; [g][gr*4+r]

    #pragma unroll 1    // rolled: keeps live ranges per-t (R5 full-unroll spilled)
    for (int t = 0; t < TSTEPS; t++) {
        float xt[GPW][4];
        #pragma unroll
        for (int g = 0; g < GPW; g++)
            #pragma unroll
            for (int r = 0; r < 4; r++)
                xt[g][r] = x[xo[g] + r * TSTEPS + t];

        f16x8 hA[GPW][2];
        if (t > 0) {
            #pragma unroll
            for (int g = 0; g < GPW; g++) {
                hA[g][0] = *(const f16x8*)(hb + g * 1024 + lane * 8);
                hA[g][1] = *(const f16x8*)(hb + g * 1024 + 512 + lane * 8);
            }
        }

        #pragma unroll
        for (int gr = 0; gr < 4; gr++) {       // j' chunk: j = gr*16 + m
            const f32x4 wv  = *(const f32x4*)&wih4[(gr * 16 + m) * 4];
            const f32x4 cbv = *(const f32x4*)&cb4[(gr * 16 + m) * 4];

            f32x4 ag[GPW][4];
            #pragma unroll
            for (int g = 0; g < GPW; g++)
                #pragma unroll
                for (int G = 0; G < 4; G++)
                    #pragma unroll
                    for (int r = 0; r < 4; r++)
                        ag[g][G][r] = fmaf(xt[g][r], wv[G], cbv[G]);

            if (t > 0) {
                #pragma unroll
                for (int G = 0; G < 4; G++) {
                    const int n = G * 4 + gr;
                    const f16x8 w0 = *(const f16x8*)(Wf + (n * 2 + 0) * 512 + lane * 8);
                    const f16x8 w1 = *(const f16x8*)(Wf + (n * 2 + 1) * 512 + lane * 8);
                    #pragma unroll
                    for (int g = 0; g < GPW; g++) {   // reuse w0/w1 for both groups
                        ag[g][G] = __builtin_amdgcn_mfma_f32_16x16x32_f16(hA[g][0], w0, ag[g][G], 0, 0, 0);
                        ag[g][G] = __builtin_amdgcn_mfma_f32_16x16x32_f16(hA[g][1], w1, ag[g][G], 0, 0, 0);
                    }
                }
            }

            #pragma unroll
            for (int g = 0; g < GPW; g++) {
                #pragma unroll
                for (int r = 0; r < 4; r++) {
                    const int u = gr * 4 + r;
                    float cs, so;
                    if (t == 0) {
                        const float ei = ex2_(-ag[g][0][r]);
                        const float eg = ex2_( ag[g][2][r]);
                        const float eo = ex2_(-ag[g][3][r]);
                        const float si = rcp_(1.0f + ei);
                        const float dg = 1.0f + eg, dn = 1.0f + eo;
                        const float r2 = rcp_(dn * dg);
                        so = r2 * dg;
                        const float rg  = r2 * dn;
                        const float tgs = fmaf(rg, -4.0f * L2E, 2.0f * L2E);
                        cs = si * tgs;
                    } else {
                        const float ei = ex2_(-ag[g][0][r]);
                        const float ef = ex2_(-ag[g][1][r]);
                        const float eg = ex2_( ag[g][2][r]);
                        const float eo = ex2_(-ag[g][3][r]);
                        const float di = 1.0f + ei, df = 1.0f + ef;
                        const float dg = 1.0f + eg, dn = 1.0f + eo;
                        const float r1 = rcp_(di * df);          // shared rcp (i,f)
                        const float si = r1 * df, sf = r1 * di;
                        const float r2 = rcp_(dn * dg);          // shared rcp (o,g)
                        so = r2 * dg;
                        const float rg  = r2 * dn;
                        const float tgs = fmaf(rg, -4.0f * L2E, 2.0f * L2E);
                        cs = fmaf(sf, c[g][u], si * tgs);
                    }
                    c[g][u] = cs;                                 // scaled domain
                    const float rc = rcp_(ex2_(cs) + 1.0f);       // tanh(c) = 1-2*rc
                    const float hn = so * fmaf(rc, -2.0f, 1.0f);
                    // scatter h (fp16) into A-fragment slots (also at t=4, for FC)
                    const int lp = (q * 4 + r) + 16 * (2 * (gr & 1) + (m >> 3));
                    hb[g * 1024 + (gr >> 1) * 512 + lp * 8 + (m & 7)] = (_Float16)hn;
                }
            }
        }
    }

    // ---- FC epilogue: read final h back from hbuf (A-layout, same wave) ----
    // lane holds h[e = m][k = kh*32 + q*8 + i]; reduce over lanes m, m+16, m+32, m+48
    float p[GPW] = {0.0f, 0.0f};
    #pragma unroll
    for (int kh = 0; kh < 2; kh++) {
        const float* wp = W_fc + kh * 32 + q * 8;
        const f32x4 wa = *(const f32x4*)wp;
        const f32x4 wb = *(const f32x4*)(wp + 4);
        #pragma unroll
        for (int g = 0; g < GPW; g++) {
            const f16x8 h8 = *(const f16x8*)(hb + g * 1024 + kh * 512 + lane * 8);
            #pragma unroll
            for (int i = 0; i < 4; i++) {
                p[g] = fmaf((float)h8[i],     wa[i], p[g]);
                p[g] = fmaf((float)h8[4 + i], wb[i], p[g]);
            }
        }
    }
    const float bfc = b_fc[0];
    #pragma unroll
    for (int g = 0; g < GPW; g++) {
        p[g] += __shfl_xor(p[g], 16, 64);
        p[g] += __shfl_xor(p[g], 32, 64);
        if (lane < 16) {
            const int e = eg0 + g * 16 + lane;
            if (e < B) out[e] = p[g] + bfc;
        }
    }
}

extern "C" void kernel_launch(void* const* d_in, const int* in_sizes, int n_in,
                              void* d_out, int out_size, void* d_ws, size_t ws_size,
                              hipStream_t stream) {
    const float* x    = (const float*)d_in[0];
    const float* W_ih = (const float*)d_in[1];
    const float* W_hh = (const float*)d_in[2];
    const float* b_ih = (const float*)d_in[3];
    const float* b_hh = (const float*)d_in[4];
    const float* W_fc = (const float*)d_in[5];
    const float* b_fc = (const float*)d_in[6];
    float* out = (float*)d_out;

    const int B = in_sizes[0] / TSTEPS;   // x is [B, T, 1]
    const int grid = (B + EPB - 1) / EPB;
    lstm_mfma_kernel<<<grid, BLOCK, 0, stream>>>(x, W_ih, W_hh, b_ih, b_hh,
                                                 W_fc, b_fc, out, B);
}

// Round 9
// 174.176 us; speedup vs baseline: 1.4875x; 1.4875x over previous
//
#include <hip/hip_runtime.h>

#define HDIM   64
#define TSTEPS 5
#define WAVES  8
#define BLOCK  (WAVES * 64)
#define GPW    1                    // batch groups (of 16) per wave
#define EPW    (GPW * 16)           // 16 batch per wave
#define EPB    (WAVES * EPW)        // 128 batch per block

typedef _Float16 f16x8 __attribute__((ext_vector_type(8)));
typedef float    f32x4 __attribute__((ext_vector_type(4)));

#define L2E 1.44269504088896340736f   // log2(e)

__device__ __forceinline__ float rcp_(float x) { return __builtin_amdgcn_rcpf(x); }
__device__ __forceinline__ float ex2_(float x) { return __builtin_amdgcn_exp2f(x); }

// Gates as D[m=batch e][n=gate row j'] = A[e][k] * B[k][j'] + C(bias + x*W_ih)
// B = W_hh^T staged once in LDS (pre-scaled by log2e; 2*log2e for g-gate).
//
// CONFIG (R4-R8 measured map):
//  - GPW=1: live set ~60-84 arch VGPRs. The unified file is split ~half
//    VGPR / half AGPR, so the usable arch budget is cap/2. GPW=2's ~128-reg
//    live set needs cap=256 -> 2 waves/SIMD -> SIMD-starved (R7: 133 us).
//    GPW=1 at cap=128 fits clean (R4: 60 VGPR, 0 spill, 105 us).
//  - WAVES=8, LDS=50 KB -> 3 blocks/CU = 24 waves/CU (6/SIMD) — enough TLP
//    for the trans-latency-bound inner loop.
//  - Activation uses paired reciprocals: 8 trans/gate-set (4 exp2 + 3 rcp +
//    1 exp2 for tanh(c)), validated in R5-R8 (absmax 9.77e-4).
//  - t-loop rolled; full unroll doubles live ranges -> spill (R5).
//
// 16x16x32 f16 layouts (verified R3-R8, absmax 9.8e-4):
//   A-frag: lane holds A[m=lane&15][k = kh*32 + (lane>>4)*8 + i], i=0..7
//   B-frag: lane holds B[k = kh*32 + (lane>>4)*8 + i][n = ntile*16 + (lane&15)]
//   C/D:    lane holds D[m = (lane>>4)*4 + reg][n = ntile*16 + (lane&15)]
__global__ __launch_bounds__(BLOCK, 4) void lstm_mfma_kernel(
    const float* __restrict__ x,      // [B, T, 1]
    const float* __restrict__ W_ih,   // [256, 1]
    const float* __restrict__ W_hh,   // [256, 64]
    const float* __restrict__ b_ih,   // [256]
    const float* __restrict__ b_hh,   // [256]
    const float* __restrict__ W_fc,   // [1, 64]
    const float* __restrict__ b_fc,   // [1]
    float* __restrict__ out,          // [B, 1]
    int B)
{
    __shared__ _Float16 Wf[2048 * 8];               // 32 KB, B-fragments
    __shared__ _Float16 hbuf[WAVES * GPW * 1024];   // 16 KB, per-wave h A-frags
    __shared__ float    wih4[256];                  // [jl*4+G], pre-scaled
    __shared__ float    cb4[256];                   // [jl*4+G], pre-scaled b_ih+b_hh

    const int tid = threadIdx.x;

    // ---- one-time staging ----
    #pragma unroll
    for (int s0 = 0; s0 < 2048; s0 += BLOCK) {
        const int s  = s0 + tid;
        const int ln = s & 63;
        const int kh = (s >> 6) & 1;
        const int n  = s >> 7;                             // N-tile, gate G = n>>2
        const float scl = ((n >> 2) == 2) ? (2.0f * L2E) : L2E;
        const int j  = n * 16 + (ln & 15);
        const int k0 = kh * 32 + ((ln >> 4) & 3) * 8;
        const float* src = W_hh + j * HDIM + k0;
        #pragma unroll
        for (int i = 0; i < 8; i++)
            Wf[s * 8 + i] = (_Float16)(src[i] * scl);
    }
    if (tid < 256) {
        const int jl = tid >> 2, G = tid & 3;
        const float scl = (G == 2) ? (2.0f * L2E) : L2E;
        wih4[tid] = W_ih[G * 64 + jl] * scl;
        cb4[tid]  = (b_ih[G * 64 + jl] + b_hh[G * 64 + jl]) * scl;
    }
    __syncthreads();   // only barrier

    const int lane = tid & 63;
    const int wave = tid >> 6;
    const int m    = lane & 15;
    const int q    = lane >> 4;
    const int eg0  = (blockIdx.x * WAVES + wave) * EPW;

    _Float16* hb = hbuf + wave * (GPW * 1024);

    // x element offsets: e = eg0 + g*16 + q*4 + r  -> offset e*TSTEPS (+ r*TSTEPS + t)
    int xo[GPW];
    #pragma unroll
    for (int g = 0; g < GPW; g++) {
        int e4 = eg0 + g * 16 + q * 4;
        if (e4 > B - 4) e4 = (B >= 4) ? (B - 4) : 0;   // defensive; grid is exact
        xo[g] = e4 * TSTEPS;
    }

    float c[GPW][16];   // cell state, scaled by 2*log2e; [g][gr*4+r]

    #pragma unroll 1    // rolled: keeps live ranges per-t (R5 full-unroll spilled)
    for (int t = 0; t < TSTEPS; t++) {
        float xt[GPW][4];
        #pragma unroll
        for (int g = 0; g < GPW; g++)
            #pragma unroll
            for (int r = 0; r < 4; r++)
                xt[g][r] = x[xo[g] + r * TSTEPS + t];

        f16x8 hA[GPW][2];
        if (t > 0) {
            #pragma unroll
            for (int g = 0; g < GPW; g++) {
                hA[g][0] = *(const f16x8*)(hb + g * 1024 + lane * 8);
                hA[g][1] = *(const f16x8*)(hb + g * 1024 + 512 + lane * 8);
            }
        }

        #pragma unroll
        for (int gr = 0; gr < 4; gr++) {       // j' chunk: j = gr*16 + m
            const f32x4 wv  = *(const f32x4*)&wih4[(gr * 16 + m) * 4];
            const f32x4 cbv = *(const f32x4*)&cb4[(gr * 16 + m) * 4];

            f32x4 ag[GPW][4];
            #pragma unroll
            for (int g = 0; g < GPW; g++)
                #pragma unroll
                for (int G = 0; G < 4; G++)
                    #pragma unroll
                    for (int r = 0; r < 4; r++)
                        ag[g][G][r] = fmaf(xt[g][r], wv[G], cbv[G]);

            if (t > 0) {
                #pragma unroll
                for (int G = 0; G < 4; G++) {
                    const int n = G * 4 + gr;
                    const f16x8 w0 = *(const f16x8*)(Wf + (n * 2 + 0) * 512 + lane * 8);
                    const f16x8 w1 = *(const f16x8*)(Wf + (n * 2 + 1) * 512 + lane * 8);
                    #pragma unroll
                    for (int g = 0; g < GPW; g++) {
                        ag[g][G] = __builtin_amdgcn_mfma_f32_16x16x32_f16(hA[g][0], w0, ag[g][G], 0, 0, 0);
                        ag[g][G] = __builtin_amdgcn_mfma_f32_16x16x32_f16(hA[g][1], w1, ag[g][G], 0, 0, 0);
                    }
                }
            }

            #pragma unroll
            for (int g = 0; g < GPW; g++) {
                #pragma unroll
                for (int r = 0; r < 4; r++) {
                    const int u = gr * 4 + r;
                    float cs, so;
                    if (t == 0) {
                        const float ei = ex2_(-ag[g][0][r]);
                        const float eg = ex2_( ag[g][2][r]);
                        const float eo = ex2_(-ag[g][3][r]);
                        const float si = rcp_(1.0f + ei);
                        const float dg = 1.0f + eg, dn = 1.0f + eo;
                        const float r2 = rcp_(dn * dg);
                        so = r2 * dg;
                        const float rg  = r2 * dn;
                        const float tgs = fmaf(rg, -4.0f * L2E, 2.0f * L2E);
                        cs = si * tgs;
                    } else {
                        const float ei = ex2_(-ag[g][0][r]);
                        const float ef = ex2_(-ag[g][1][r]);
                        const float eg = ex2_( ag[g][2][r]);
                        const float eo = ex2_(-ag[g][3][r]);
                        const float di = 1.0f + ei, df = 1.0f + ef;
                        const float dg = 1.0f + eg, dn = 1.0f + eo;
                        const float r1 = rcp_(di * df);          // shared rcp (i,f)
                        const float si = r1 * df, sf = r1 * di;
                        const float r2 = rcp_(dn * dg);          // shared rcp (o,g)
                        so = r2 * dg;
                        const float rg  = r2 * dn;
                        const float tgs = fmaf(rg, -4.0f * L2E, 2.0f * L2E);
                        cs = fmaf(sf, c[g][u], si * tgs);
                    }
                    c[g][u] = cs;                                 // scaled domain
                    const float rc = rcp_(ex2_(cs) + 1.0f);       // tanh(c) = 1-2*rc
                    const float hn = so * fmaf(rc, -2.0f, 1.0f);
                    // scatter h (fp16) into A-fragment slots (also at t=4, for FC)
                    const int lp = (q * 4 + r) + 16 * (2 * (gr & 1) + (m >> 3));
                    hb[g * 1024 + (gr >> 1) * 512 + lp * 8 + (m & 7)] = (_Float16)hn;
                }
            }
        }
    }

    // ---- FC epilogue: read final h back from hbuf (A-layout, same wave) ----
    // lane holds h[e = m][k = kh*32 + q*8 + i]; reduce over lanes m, m+16, m+32, m+48
    float p[GPW];
    #pragma unroll
    for (int g = 0; g < GPW; g++) p[g] = 0.0f;
    #pragma unroll
    for (int kh = 0; kh < 2; kh++) {
        const float* wp = W_fc + kh * 32 + q * 8;
        const f32x4 wa = *(const f32x4*)wp;
        const f32x4 wb = *(const f32x4*)(wp + 4);
        #pragma unroll
        for (int g = 0; g < GPW; g++) {
            const f16x8 h8 = *(const f16x8*)(hb + g * 1024 + kh * 512 + lane * 8);
            #pragma unroll
            for (int i = 0; i < 4; i++) {
                p[g] = fmaf((float)h8[i],     wa[i], p[g]);
                p[g] = fmaf((float)h8[4 + i], wb[i], p[g]);
            }
        }
    }
    const float bfc = b_fc[0];
    #pragma unroll
    for (int g = 0; g < GPW; g++) {
        p[g] += __shfl_xor(p[g], 16, 64);
        p[g] += __shfl_xor(p[g], 32, 64);
        if (lane < 16) {
            const int e = eg0 + g * 16 + lane;
            if (e < B) out[e] = p[g] + bfc;
        }
    }
}

extern "C" void kernel_launch(void* const* d_in, const int* in_sizes, int n_in,
                              void* d_out, int out_size, void* d_ws, size_t ws_size,
                              hipStream_t stream) {
    const float* x    = (const float*)d_in[0];
    const float* W_ih = (const float*)d_in[1];
    const float* W_hh = (const float*)d_in[2];
    const float* b_ih = (const float*)d_in[3];
    const float* b_hh = (const float*)d_in[4];
    const float* W_fc = (const float*)d_in[5];
    const float* b_fc = (const float*)d_in[6];
    float* out = (float*)d_out;

    const int B = in_sizes[0] / TSTEPS;   // x is [B, T, 1]
    const int grid = (B + EPB - 1) / EPB;
    lstm_mfma_kernel<<<grid, BLOCK, 0, stream>>>(x, W_ih, W_hh, b_ih, b_hh,
                                                 W_fc, b_fc, out, B);
}